// Round 4
// baseline (18468.832 us; speedup 1.0000x reference)
//
#include <hip/hip_runtime.h>
#include <math.h>

// Problem constants (fixed by setup_inputs)
#define Bz 64
#define Tz 1024
#define Dz 512
#define Hz 256
#define Gz 1024   // 4*H
#define Kz 20

typedef float f32x4 __attribute__((ext_vector_type(4)));
typedef short bf16x8 __attribute__((ext_vector_type(8)));

__device__ __forceinline__ float sigf(float x) { return 1.0f / (1.0f + __expf(-x)); }

__device__ __forceinline__ unsigned short bf16_rne(float f) {
    unsigned u = __float_as_uint(f);
    return (unsigned short)((u + 0x7fffu + ((u >> 16) & 1u)) >> 16);
}
__device__ __forceinline__ float bf16_f(unsigned short s) {
    return __uint_as_float(((unsigned)s) << 16);
}

// ws map (dwords): [0,2048) flags | [2048,100352) h planes (u64-aligned) |
// [100352,133120) cbuf | [133120,...) gates
#define WS_HQ   2048
#define WS_CB   100352
#define WS_GT   133120

// ---------------------------------------------------------------------------
__global__ __launch_bounds__(256) void init_ws(int* p) {
    int i = blockIdx.x * 256 + threadIdx.x;
    if (i < WS_GT) p[i] = 0;
}

// ---------------------------------------------------------------------------
// Input-gate precompute GEMM (fp32, LDS-tiled 64x64, 4x4 microtile).
// G[dir][row][sl][b] = bias[row] + sum_k W_ih[row][k] * x[b][t(dir,sl)][k]
// ---------------------------------------------------------------------------
__global__ __launch_bounds__(256) void gates_gemm(
    const float* __restrict__ x,
    const float* __restrict__ Wf, const float* __restrict__ Wb,
    const float* __restrict__ bf, const float* __restrict__ bb,
    float* __restrict__ G, int Tc, int base)
{
    __shared__ __align__(16) float As[16][68];
    __shared__ __align__(16) float Bs[16][68];
    const int tid   = threadIdx.x;
    const int mtile = blockIdx.x;
    const int sl    = blockIdx.y;
    const int dir   = blockIdx.z;

    const float* W    = dir ? Wb : Wf;
    const float* bias = dir ? bb : bf;
    const int s = base + sl;
    const int t = dir ? (Tz - 1 - s) : s;

    const int lr = tid >> 2;
    const int lk = (tid & 3) * 4;
    const float* Arow = W + (size_t)(mtile * 64 + lr) * Dz;
    const float* Brow = x + ((size_t)lr * Tz + t) * Dz;

    const int mg = tid >> 4;
    const int ng = tid & 15;
    float acc[4][4] = {};

    for (int kt = 0; kt < Dz; kt += 16) {
        float4 a4 = *(const float4*)(Arow + kt + lk);
        float4 b4 = *(const float4*)(Brow + kt + lk);
        __syncthreads();
        As[lk + 0][lr] = a4.x; As[lk + 1][lr] = a4.y;
        As[lk + 2][lr] = a4.z; As[lk + 3][lr] = a4.w;
        Bs[lk + 0][lr] = b4.x; Bs[lk + 1][lr] = b4.y;
        Bs[lk + 2][lr] = b4.z; Bs[lk + 3][lr] = b4.w;
        __syncthreads();
#pragma unroll
        for (int kk = 0; kk < 16; ++kk) {
            float4 av = *(const float4*)&As[kk][mg * 4];
            float4 bv = *(const float4*)&Bs[kk][ng * 4];
            acc[0][0] = fmaf(av.x, bv.x, acc[0][0]);
            acc[0][1] = fmaf(av.x, bv.y, acc[0][1]);
            acc[0][2] = fmaf(av.x, bv.z, acc[0][2]);
            acc[0][3] = fmaf(av.x, bv.w, acc[0][3]);
            acc[1][0] = fmaf(av.y, bv.x, acc[1][0]);
            acc[1][1] = fmaf(av.y, bv.y, acc[1][1]);
            acc[1][2] = fmaf(av.y, bv.z, acc[1][2]);
            acc[1][3] = fmaf(av.y, bv.w, acc[1][3]);
            acc[2][0] = fmaf(av.z, bv.x, acc[2][0]);
            acc[2][1] = fmaf(av.z, bv.y, acc[2][1]);
            acc[2][2] = fmaf(av.z, bv.z, acc[2][2]);
            acc[2][3] = fmaf(av.z, bv.w, acc[2][3]);
            acc[3][0] = fmaf(av.w, bv.x, acc[3][0]);
            acc[3][1] = fmaf(av.w, bv.y, acc[3][1]);
            acc[3][2] = fmaf(av.w, bv.z, acc[3][2]);
            acc[3][3] = fmaf(av.w, bv.w, acc[3][3]);
        }
    }
#pragma unroll
    for (int i = 0; i < 4; ++i) {
        int row = mtile * 64 + mg * 4 + i;
        float bvs = bias[row];
        float4 o;
        o.x = acc[i][0] + bvs; o.y = acc[i][1] + bvs;
        o.z = acc[i][2] + bvs; o.w = acc[i][3] + bvs;
        *(float4*)(G + (((size_t)dir * Gz + row) * Tc + sl) * 64 + ng * 4) = o;
    }
}

// ---------------------------------------------------------------------------
// Persistent recurrent kernel v4 — MFMA, split-bf16 (3-plane h x 3-plane W,
// 6 product terms ~ fp32-faithful). 32 blocks = 2 dirs x 16 h-groups; block
// owns h-indices {16g..16g+15} x all 64 batches (rows q*256+x, q=gate).
//
// W_hh lives in REGISTERS as A-fragments (built once). h is exchanged as 3
// bf16 planes [b][k] in ws; consumers load B-fragments DIRECTLY from global
// into registers via 8B agent-atomic loads (no LDS round trip, no stale-L2
// risk). Gate i/f/g/o cross-wave exchange via 16KB LDS. Step barrier =
// per-block monotone stamp + wave-parallel poll (R3 scheme, 16 flags/dir).
//
// MFMA layouts (guide §3, m89/m91/m120): 16x16x32_bf16
//   A: a[m = lane&15][k = (lane>>4)*8 + j]      (j = elem 0..7)
//   B: b[k = (lane>>4)*8 + j][n = lane&15]
//   D: d[row = (lane>>4)*4 + r][col = lane&15]  (r = reg 0..3)
// ---------------------------------------------------------------------------
__global__ __launch_bounds__(256, 1) void lstm_rec(
    const float* __restrict__ G,            // [2][1024][Tc][64]
    const float* __restrict__ Whf, const float* __restrict__ Whb,
    unsigned long long* __restrict__ hq,    // [par][dir][plane][64 b][64 qw]
    float* __restrict__ cbuf,               // [2][256][64]
    float* __restrict__ out1,               // lstm_o [64][1024][512]
    int* pflag, int Tc, int base)
{
    __shared__ float gl[4][16][64];         // 16 KB gate exchange

    const int tid  = threadIdx.x;
    const int lane = tid & 63;
    const int wv   = tid >> 6;      // wave 0..3
    const int p    = wv >> 1;       // gate-pair: gates {2p, 2p+1}
    const int nh   = wv & 1;        // batch half: b in [nh*32, nh*32+32)
    const int dir  = blockIdx.x >> 4;
    const int g    = blockIdx.x & 15;   // h-group: x in [16g, 16g+16)
    const float* Whh = dir ? Whb : Whf;

    const int lm = lane & 15;       // m/n within tile
    const int lq = lane >> 4;       // quad

    // ---- build W A-fragments in registers: [plane][gm][kt] ----
    bf16x8 Wfr[3][2][8];
#pragma unroll
    for (int gm = 0; gm < 2; ++gm) {
        const float* wr = Whh + (size_t)((p * 2 + gm) * Hz + g * 16 + lm) * Hz;
#pragma unroll
        for (int kt = 0; kt < 8; ++kt) {
            const int kb = kt * 32 + lq * 8;
            float4 f0 = *(const float4*)(wr + kb);
            float4 f1 = *(const float4*)(wr + kb + 4);
            float ff[8] = {f0.x, f0.y, f0.z, f0.w, f1.x, f1.y, f1.z, f1.w};
            union { unsigned short s[8]; bf16x8 v; } uh, um, ul;
#pragma unroll
            for (int j = 0; j < 8; ++j) {
                unsigned short hb = bf16_rne(ff[j]);
                float r1 = ff[j] - bf16_f(hb);
                unsigned short mb = bf16_rne(r1);
                unsigned short lb = bf16_rne(r1 - bf16_f(mb));
                uh.s[j] = hb; um.s[j] = mb; ul.s[j] = lb;
            }
            Wfr[0][gm][kt] = uh.v; Wfr[1][gm][kt] = um.v; Wfr[2][gm][kt] = ul.v;
        }
    }

    // ---- c state: thread (b = tid&63, x = (tid>>6)*4 + i) ----
    const int cb = tid & 63;
    const int cx = tid >> 6;                // x-quad index
    float c_reg[4];
#pragma unroll
    for (int i = 0; i < 4; ++i)
        c_reg[i] = cbuf[((size_t)dir * Hz + g * 16 + cx * 4 + i) * 64 + cb];
    __syncthreads();

    for (int sl = 0; sl < Tc; ++sl) {
        const int s = base + sl;

        // ---- accumulator init from G (independent of h; issues pre-poll) ----
        f32x4 acc[2][2];
#pragma unroll
        for (int gm = 0; gm < 2; ++gm)
#pragma unroll
            for (int nt = 0; nt < 2; ++nt)
#pragma unroll
                for (int r = 0; r < 4; ++r)
                    acc[gm][nt][r] = G[(((size_t)dir * Gz + (p * 2 + gm) * Hz
                                         + g * 16 + lq * 4 + r) * Tc + sl) * 64
                                       + nh * 32 + nt * 16 + lm];

        // ---- step barrier: all 16 producers of this dir stamped >= s ----
        if (s > 0) {
            const int* fp = pflag + dir * 16 + (lane & 15);
            for (;;) {
                int v = __hip_atomic_load(fp, __ATOMIC_RELAXED,
                                          __HIP_MEMORY_SCOPE_AGENT);
                if (__all(v >= s)) break;
                __builtin_amdgcn_s_sleep(1);
            }
            __syncthreads();
        }

        // ---- B-fragment loads (direct global->reg) + MFMA, pipelined ----
        const unsigned long long* hbase =
            hq + (size_t)((s & 1) * 2 + dir) * 3 * 4096;
        // lane's qword index for (nt, kt, half): b*64 + kt*8 + lq*2 + half
        unsigned long long hf[2][2][3][2];  // [buf][nt][plane][half]
#pragma unroll
        for (int nt = 0; nt < 2; ++nt) {
            const int bi = (nh * 32 + nt * 16 + lm) * 64 + lq * 2;
#pragma unroll
            for (int pl = 0; pl < 3; ++pl) {
                hf[0][nt][pl][0] = __hip_atomic_load(hbase + pl * 4096 + bi,
                                       __ATOMIC_RELAXED, __HIP_MEMORY_SCOPE_AGENT);
                hf[0][nt][pl][1] = __hip_atomic_load(hbase + pl * 4096 + bi + 1,
                                       __ATOMIC_RELAXED, __HIP_MEMORY_SCOPE_AGENT);
            }
        }
#pragma unroll
        for (int kt = 0; kt < 8; ++kt) {
            const int cur = kt & 1;
            if (kt < 7) {
#pragma unroll
                for (int nt = 0; nt < 2; ++nt) {
                    const int bi = (nh * 32 + nt * 16 + lm) * 64
                                   + (kt + 1) * 8 + lq * 2;
#pragma unroll
                    for (int pl = 0; pl < 3; ++pl) {
                        hf[cur ^ 1][nt][pl][0] =
                            __hip_atomic_load(hbase + pl * 4096 + bi,
                                __ATOMIC_RELAXED, __HIP_MEMORY_SCOPE_AGENT);
                        hf[cur ^ 1][nt][pl][1] =
                            __hip_atomic_load(hbase + pl * 4096 + bi + 1,
                                __ATOMIC_RELAXED, __HIP_MEMORY_SCOPE_AGENT);
                    }
                }
            }
#pragma unroll
            for (int nt = 0; nt < 2; ++nt) {
                union { unsigned long long q[2]; bf16x8 v; } bh, bm, bl;
                bh.q[0] = hf[cur][nt][0][0]; bh.q[1] = hf[cur][nt][0][1];
                bm.q[0] = hf[cur][nt][1][0]; bm.q[1] = hf[cur][nt][1][1];
                bl.q[0] = hf[cur][nt][2][0]; bl.q[1] = hf[cur][nt][2][1];
#pragma unroll
                for (int gm = 0; gm < 2; ++gm) {
                    f32x4 a = acc[gm][nt];
                    a = __builtin_amdgcn_mfma_f32_16x16x32_bf16(Wfr[0][gm][kt], bh.v, a, 0, 0, 0);
                    a = __builtin_amdgcn_mfma_f32_16x16x32_bf16(Wfr[0][gm][kt], bm.v, a, 0, 0, 0);
                    a = __builtin_amdgcn_mfma_f32_16x16x32_bf16(Wfr[0][gm][kt], bl.v, a, 0, 0, 0);
                    a = __builtin_amdgcn_mfma_f32_16x16x32_bf16(Wfr[1][gm][kt], bh.v, a, 0, 0, 0);
                    a = __builtin_amdgcn_mfma_f32_16x16x32_bf16(Wfr[1][gm][kt], bm.v, a, 0, 0, 0);
                    a = __builtin_amdgcn_mfma_f32_16x16x32_bf16(Wfr[2][gm][kt], bh.v, a, 0, 0, 0);
                    acc[gm][nt] = a;
                }
            }
        }

        // ---- gate exchange through LDS ----
#pragma unroll
        for (int gm = 0; gm < 2; ++gm)
#pragma unroll
            for (int nt = 0; nt < 2; ++nt)
#pragma unroll
                for (int r = 0; r < 4; ++r)
                    gl[p * 2 + gm][lq * 4 + r][nh * 32 + nt * 16 + lm] =
                        acc[gm][nt][r];
        __syncthreads();

        // ---- activations: thread (cb, x = cx*4+i) ----
        float hval[4];
#pragma unroll
        for (int i = 0; i < 4; ++i) {
            const int x = cx * 4 + i;
            float gi = sigf(gl[0][x][cb]);
            float gf = sigf(gl[1][x][cb]);
            float gg = tanhf(gl[2][x][cb]);
            float go = sigf(gl[3][x][cb]);
            c_reg[i] = gf * c_reg[i] + gi * gg;
            hval[i] = go * tanhf(c_reg[i]);
        }

        // ---- split h 3-way, pack 4 consecutive k per plane, store coherent ----
        unsigned long long qh = 0, qm = 0, qlo = 0;
#pragma unroll
        for (int i = 0; i < 4; ++i) {
            unsigned short hb = bf16_rne(hval[i]);
            float r1 = hval[i] - bf16_f(hb);
            unsigned short mb = bf16_rne(r1);
            unsigned short lb = bf16_rne(r1 - bf16_f(mb));
            qh  |= (unsigned long long)hb << (16 * i);
            qm  |= (unsigned long long)mb << (16 * i);
            qlo |= (unsigned long long)lb << (16 * i);
        }
        unsigned long long* hdst =
            hq + (size_t)(((s + 1) & 1) * 2 + dir) * 3 * 4096
               + (size_t)cb * 64 + g * 4 + cx;
        __hip_atomic_store(hdst,            qh,  __ATOMIC_RELAXED, __HIP_MEMORY_SCOPE_AGENT);
        __hip_atomic_store(hdst + 4096,     qm,  __ATOMIC_RELAXED, __HIP_MEMORY_SCOPE_AGENT);
        __hip_atomic_store(hdst + 2 * 4096, qlo, __ATOMIC_RELAXED, __HIP_MEMORY_SCOPE_AGENT);

        asm volatile("s_waitcnt vmcnt(0)" ::: "memory");
        __syncthreads();
        if (tid == 0)
            __hip_atomic_store(pflag + dir * 16 + g, s + 1,
                               __ATOMIC_RELAXED, __HIP_MEMORY_SCOPE_AGENT);

        // ---- non-critical lstm_o store (after signal) ----
        const int tt = dir ? (Tz - 1 - s) : s;
#pragma unroll
        for (int i = 0; i < 4; ++i)
            out1[((size_t)cb * Tz + tt) * Dz + dir * Hz + g * 16 + cx * 4 + i] =
                hval[i];
    }

#pragma unroll
    for (int i = 0; i < 4; ++i)
        cbuf[((size_t)dir * Hz + g * 16 + cx * 4 + i) * 64 + cb] = c_reg[i];
}

// ---------------------------------------------------------------------------
// Head: logits -> 20 smallest (softmax is monotone) -> indices + sgn_mask.
// ---------------------------------------------------------------------------
__global__ __launch_bounds__(256) void head_kernel(
    const float* __restrict__ out1, const float* __restrict__ lin_w,
    const float* __restrict__ lin_b, const unsigned char* __restrict__ mask8,
    float* __restrict__ out0, float* __restrict__ out2)
{
    __shared__ __align__(16) float lw[Dz];
    __shared__ float llog[Tz];
    __shared__ unsigned char hit[Tz];
    __shared__ float redv[4];
    __shared__ int   redi[4];

    const int tid = threadIdx.x;
    const int bb  = blockIdx.x;
    for (int i = tid; i < Dz; i += 256) lw[i] = lin_w[i];
    for (int i = tid; i < Tz; i += 256) hit[i] = 0;
    __syncthreads();

    const int w = tid >> 6, lane = tid & 63;
    const float lbv = lin_b[0];
    for (int t = w; t < Tz; t += 4) {
        const float* rp = out1 + ((size_t)bb * Tz + t) * Dz + lane * 8;
        float4 a0 = *(const float4*)rp;
        float4 a1 = *(const float4*)(rp + 4);
        const float* wp = lw + lane * 8;
        float ps = a0.x * wp[0] + a0.y * wp[1] + a0.z * wp[2] + a0.w * wp[3]
                 + a1.x * wp[4] + a1.y * wp[5] + a1.z * wp[6] + a1.w * wp[7];
        for (int o = 32; o; o >>= 1) ps += __shfl_down(ps, o);
        if (lane == 0) llog[t] = ps + lbv;
    }
    __syncthreads();

    for (int it = 0; it < Kz; ++it) {
        float bv = 3.4e38f; int bi = Tz - 1;
        for (int t = tid; t < Tz; t += 256) {
            float v = llog[t];
            if (v < bv) { bv = v; bi = t; }
        }
        for (int o = 32; o; o >>= 1) {
            float ov = __shfl_down(bv, o);
            int   oi = __shfl_down(bi, o);
            if (ov < bv || (ov == bv && oi < bi)) { bv = ov; bi = oi; }
        }
        if (lane == 0) { redv[w] = bv; redi[w] = bi; }
        __syncthreads();
        if (tid == 0) {
            for (int qq = 1; qq < 4; ++qq)
                if (redv[qq] < bv || (redv[qq] == bv && redi[qq] < bi)) { bv = redv[qq]; bi = redi[qq]; }
            out0[bb * Kz + it] = (float)bi;
            llog[bi] = 3.4e38f;
            hit[bi] = 1;
        }
        __syncthreads();
    }
    for (int t = tid; t < Tz; t += 256) {
        bool mv = mask8[(size_t)bb * Tz + t] != 0;
        out2[(size_t)bb * Tz + t] = (mv && !hit[t]) ? 1.0f : 0.0f;
    }
}

// ---------------------------------------------------------------------------
// In-place LayerNorm over last dim (512), eps=1e-5. One wave per row.
// ---------------------------------------------------------------------------
__global__ __launch_bounds__(256) void ln_kernel(
    float* __restrict__ out1, const float* __restrict__ ln_g,
    const float* __restrict__ ln_b)
{
    const int tid = threadIdx.x;
    const int w = tid >> 6, lane = tid & 63;
    const size_t row = (size_t)blockIdx.x * 4 + w;
    float* rp = out1 + row * Dz + lane * 8;
    float4 a0 = *(float4*)rp;
    float4 a1 = *(float4*)(rp + 4);
    float s  = a0.x + a0.y + a0.z + a0.w + a1.x + a1.y + a1.z + a1.w;
    float sq = a0.x*a0.x + a0.y*a0.y + a0.z*a0.z + a0.w*a0.w
             + a1.x*a1.x + a1.y*a1.y + a1.z*a1.z + a1.w*a1.w;
    for (int o = 32; o; o >>= 1) { s += __shfl_down(s, o); sq += __shfl_down(sq, o); }
    s  = __shfl(s, 0);
    sq = __shfl(sq, 0);
    const float mu  = s * (1.0f / Dz);
    const float var = sq * (1.0f / Dz) - mu * mu;
    const float rs  = rsqrtf(var + 1e-5f);
    const float* gp = ln_g + lane * 8;
    const float* bp = ln_b + lane * 8;
    a0.x = (a0.x - mu) * rs * gp[0] + bp[0];
    a0.y = (a0.y - mu) * rs * gp[1] + bp[1];
    a0.z = (a0.z - mu) * rs * gp[2] + bp[2];
    a0.w = (a0.w - mu) * rs * gp[3] + bp[3];
    a1.x = (a1.x - mu) * rs * gp[4] + bp[4];
    a1.y = (a1.y - mu) * rs * gp[5] + bp[5];
    a1.z = (a1.z - mu) * rs * gp[6] + bp[6];
    a1.w = (a1.w - mu) * rs * gp[7] + bp[7];
    *(float4*)rp = a0;
    *(float4*)(rp + 4) = a1;
}

// ---------------------------------------------------------------------------
extern "C" void kernel_launch(void* const* d_in, const int* in_sizes, int n_in,
                              void* d_out, int out_size, void* d_ws, size_t ws_size,
                              hipStream_t stream)
{
    (void)in_sizes; (void)n_in; (void)out_size;
    const float* x     = (const float*)d_in[0];
    const float* Wif   = (const float*)d_in[1];
    const float* Whf   = (const float*)d_in[2];
    const float* bf    = (const float*)d_in[3];
    const float* Wib   = (const float*)d_in[4];
    const float* Whb   = (const float*)d_in[5];
    const float* bb    = (const float*)d_in[6];
    const float* lin_w = (const float*)d_in[7];
    const float* lin_b = (const float*)d_in[8];
    const float* ln_g  = (const float*)d_in[9];
    const float* ln_b  = (const float*)d_in[10];
    const unsigned char* mask8 = (const unsigned char*)d_in[11];

    float* ws    = (float*)d_ws;
    int*   flags = (int*)d_ws;                              // 32 used
    unsigned long long* hqb = (unsigned long long*)(ws + WS_HQ);
    float* cbuf  = ws + WS_CB;
    float* gates = ws + WS_GT;

    const size_t fixedBytes = (size_t)WS_GT * 4;
    const size_t avail = ws_size > fixedBytes ? ws_size - fixedBytes : 0;
    int Tc = 8;
    for (int cand = 1024; cand >= 8; cand >>= 1) {
        if ((size_t)cand * (2ull * Gz * 64 * 4) <= avail) { Tc = cand; break; }
    }

    float* out0 = (float*)d_out;
    float* out1 = out0 + (size_t)Bz * Kz;
    float* out2 = out1 + (size_t)Bz * Tz * Dz;

    init_ws<<<dim3((WS_GT + 255) / 256), 256, 0, stream>>>((int*)d_ws);

    const int nChunks = Tz / Tc;
    for (int c = 0; c < nChunks; ++c) {
        const int base = c * Tc;
        gates_gemm<<<dim3(16, Tc, 2), 256, 0, stream>>>(x, Wif, Wib, bf, bb, gates, Tc, base);
        lstm_rec<<<dim3(32), 256, 0, stream>>>(gates, Whf, Whb, hqb, cbuf, out1, flags, Tc, base);
    }
    head_kernel<<<dim3(Bz), 256, 0, stream>>>(out1, lin_w, lin_b, mask8, out0, out2);
    ln_kernel<<<dim3((Bz * Tz) / 4), 256, 0, stream>>>(out1, ln_g, ln_b);
}